// Round 5
// baseline (1445.836 us; speedup 1.0000x reference)
//
#include <hip/hip_runtime.h>
#include <math.h>

typedef short short4v __attribute__((ext_vector_type(4)));
typedef short short8v __attribute__((ext_vector_type(8)));
typedef float float4v __attribute__((ext_vector_type(4)));

// ---------------- workspace layout (bytes) ----------------
#define OFF_U     ((size_t)0)          // h2 then u in-place: 512*1152*8*4 = 18,874,368
#define OFF_A     ((size_t)18874368)   // union{ w2b bf16 10.6MB | cb bf16 11.8MB }
#define OFF_WT    ((size_t)30670848)   // Wt fp32 [n][o][e][d]: 5,898,240
#define OFF_SPART ((size_t)36569088)   // [8][512][160] f32 = 2,621,440
#define OFF_VSUM  ((size_t)39190528)   // 327,680 (end 39,518,208)

__device__ inline short f2bf(float f) {
  union { float f; unsigned u; } v; v.f = f;
  unsigned r = v.u + 0x7FFFu + ((v.u >> 16) & 1u);
  return (short)(r >> 16);
}
__device__ inline float bf2f_lo(unsigned u) {
  union { unsigned u; float f; } v; v.u = u << 16; return v.f;
}
__device__ inline float bf2f_hi(unsigned u) {
  union { unsigned u; float f; } v; v.u = u & 0xFFFF0000u; return v.f;
}

// ---------------- w2 [co][ci][81] fp32 -> w2b [tap][co][ci] bf16 ----------------
__global__ __launch_bounds__(256) void transpose_w2b_kernel(
    const float* __restrict__ w2, short* __restrict__ w2b) {
  __shared__ short tl[81][66];
  int co = blockIdx.x >> 2, ci0 = (blockIdx.x & 3) * 64;
  for (int f = threadIdx.x; f < 64 * 81; f += 256) {
    int cip = f / 81, tap = f % 81;
    tl[tap][cip] = f2bf(w2[((size_t)co * 256 + ci0 + cip) * 81 + tap]);
  }
  __syncthreads();
  for (int f = threadIdx.x; f < 81 * 64; f += 256) {
    int tap = f >> 6, cip = f & 63;
    w2b[((size_t)tap * 256 + co) * 256 + ci0 + cip] = tl[tap][cip];
  }
}

// ---------------- W [n][o][d][e] -> Wt [n][o][e][d] fp32 ----------------
__global__ __launch_bounds__(256) void prep_wt_kernel(
    const float* __restrict__ W, float* __restrict__ Wt) {
  int idx = blockIdx.x * 256 + threadIdx.x;
  if (idx >= 1152 * 1280) return;
  int n = idx / 1280, r = idx - n * 1280;
  int o = r >> 7, de = r & 127;
  int d = de >> 4, e = de & 15;
  Wt[(((size_t)n * 10 + o) * 16 + e) * 8 + d] = W[idx];
}

// ---------------- fused conv1+relu+conv2, 1 batch/block, 2 blocks/CU ----------------
// 512 blocks x 256 threads. Per ci-chunk of 32: conv1 (VALU) -> h1l bf16 LDS,
// then conv2 = 81-tap bf16 MFMA implicit GEMM, M=48 (36 pos + 12 pad), N=256.
__global__ __launch_bounds__(256, 2) void conv_fused_kernel(
    const float* __restrict__ x, const float* __restrict__ w1,
    const float* __restrict__ b1v, const short* __restrict__ w2b,
    const float* __restrict__ b2v, float* __restrict__ h2) {
  __shared__ float xs[2352];        // one batch fp32 (9.4 KB)
  __shared__ float w1s[32][245];    // conv1 weights fp32, pad 245 -> odd stride (31.4 KB)
  __shared__ short h1l[400 * 36];   // h1 chunk bf16 [pos][32ci pad36] (28.8 KB)

  int b = blockIdx.x;
  int t = threadIdx.x;
  int lane = t & 63;
  int wv = t >> 6;
  int l15 = lane & 15, lq = lane >> 4;

  for (int i = t; i < 2352; i += 256) xs[i] = x[(size_t)b * 2352 + i];

  float4v acc[3][4];
#pragma unroll
  for (int mt = 0; mt < 3; mt++)
#pragma unroll
    for (int nt = 0; nt < 4; nt++) acc[mt][nt] = (float4v){0.f, 0.f, 0.f, 0.f};

  // A-row map for MFMA (m = mt*16 + l15; pad rows >=36 read row 0)
  int apx[3], apy[3];
#pragma unroll
  for (int mt = 0; mt < 3; mt++) {
    int s = mt * 16 + l15;
    if (s >= 36) s = 0;
    apx[mt] = (s / 6) * 2; apy[mt] = (s % 6) * 2;
  }
  int co[4];
#pragma unroll
  for (int nt = 0; nt < 4; nt++) co[nt] = wv * 64 + nt * 16 + l15;

  int cii = t & 31;   // ci within chunk
  int pg = t >> 5;    // 0..7: unit group

  for (int ch = 0; ch < 8; ch++) {
    int ci0 = ch * 32;
    __syncthreads();   // prev MFMA done with h1l; w1s free
    for (int i = t; i < 32 * 243; i += 256) {
      int cc = i / 243, tp = i - cc * 243;
      w1s[cc][tp] = w1[(size_t)(ci0 + cc) * 243 + tp];
    }
    __syncthreads();
    // ---- conv1: 40 units (px, py-half of 10), 5 per group ----
    float bias1 = b1v[ci0 + cii];
#pragma unroll 1
    for (int j = 0; j < 5; j++) {
      int u = pg + 8 * j;          // 0..39
      int px = u >> 1, py0 = (u & 1) * 10;
      float a10[10];
#pragma unroll
      for (int p = 0; p < 10; p++) a10[p] = 0.f;
#pragma unroll 1
      for (int cin = 0; cin < 3; cin++) {
#pragma unroll 1
        for (int kx = 0; kx < 9; kx++) {
          // 18-float window, 8B-aligned (even offset) -> float2 reads, half-wave broadcast
          const float2* xp = (const float2*)&xs[cin * 784 + (px + kx) * 28 + py0];
          float r[18];
#pragma unroll
          for (int q = 0; q < 9; q++) {
            float2 f2 = xp[q];
            r[2 * q] = f2.x; r[2 * q + 1] = f2.y;
          }
          const float* wrow = &w1s[cii][cin * 81 + kx * 9];
#pragma unroll
          for (int ky = 0; ky < 9; ky++) {
            float wv1 = wrow[ky];
#pragma unroll
            for (int p = 0; p < 10; p++)
              a10[p] = fmaf(wv1, r[p + ky], a10[p]);
          }
        }
      }
#pragma unroll
      for (int p = 0; p < 10; p++) {
        float h = a10[p] + bias1;
        h1l[(px * 20 + py0 + p) * 36 + cii] = f2bf(h > 0.f ? h : 0.f);
      }
    }
    __syncthreads();   // h1l ready
    // ---- conv2 MFMA: 81 taps, K=32 ----
    short8v bcur[4], bnxt[4];
#pragma unroll
    for (int nt = 0; nt < 4; nt++)
      bcur[nt] = *(const short8v*)(w2b + (size_t)co[nt] * 256 + lq * 8 + ci0);
#pragma unroll 1
    for (int tap = 0; tap < 81; tap++) {
      int kx = tap / 9, ky = tap - 9 * kx;
      int tn = (tap < 80) ? tap + 1 : 80;
#pragma unroll
      for (int nt = 0; nt < 4; nt++)
        bnxt[nt] = *(const short8v*)(w2b + (size_t)tn * 65536 +
                                     (size_t)co[nt] * 256 + lq * 8 + ci0);
      short8v af[3];
#pragma unroll
      for (int mt = 0; mt < 3; mt++) {
        int pos = (apx[mt] + kx) * 20 + apy[mt] + ky;
        const short4v* ap = (const short4v*)&h1l[pos * 36 + lq * 8];
        short4v lo = ap[0], hi = ap[1];
        af[mt] = __builtin_shufflevector(lo, hi, 0, 1, 2, 3, 4, 5, 6, 7);
      }
#pragma unroll
      for (int mt = 0; mt < 3; mt++)
#pragma unroll
        for (int nt = 0; nt < 4; nt++)
          acc[mt][nt] = __builtin_amdgcn_mfma_f32_16x16x32_bf16(
              af[mt], bcur[nt], acc[mt][nt], 0, 0, 0);
#pragma unroll
      for (int nt = 0; nt < 4; nt++) bcur[nt] = bnxt[nt];
    }
  }
  // ---- epilogue: bias + store h2[b][co][s] (L2 absorbs the scatter) ----
#pragma unroll
  for (int nt = 0; nt < 4; nt++) {
    float bias = b2v[co[nt]];
#pragma unroll
    for (int mt = 0; mt < 3; mt++) {
#pragma unroll
      for (int r4 = 0; r4 < 4; r4++) {
        int s = mt * 16 + lq * 4 + r4;
        if (s < 36)
          h2[((size_t)b * 256 + co[nt]) * 36 + s] = acc[mt][nt][r4] + bias;
      }
    }
  }
}

// ---------------- squash over groups of 8, IN PLACE ----------------
__global__ void squash_u_kernel(float* __restrict__ hu) {
  int g = blockIdx.x * 256 + threadIdx.x;
  if (g >= 512 * 1152) return;
  float4* p = (float4*)(hu + (size_t)g * 8);
  float4 a = p[0], bq = p[1];
  float sn = a.x*a.x + a.y*a.y + a.z*a.z + a.w*a.w +
             bq.x*bq.x + bq.y*bq.y + bq.z*bq.z + bq.w*bq.w;
  float scale = sn / (1.f + sn) / (sqrtf(sn) + 1e-6f);
  a.x *= scale; a.y *= scale; a.z *= scale; a.w *= scale;
  bq.x *= scale; bq.y *= scale; bq.z *= scale; bq.w *= scale;
  p[0] = a; p[1] = bq;
}

// ---------------- s partials: thread=(b,e), acc[o], no LDS ----------------
__global__ __launch_bounds__(256) void s_part_kernel(
    const float* __restrict__ u, const float* __restrict__ Wt,
    const short* __restrict__ cb, float* __restrict__ spart) {
  int bt = blockIdx.x, nc = blockIdx.y;
  int t = threadIdx.x;
  int bq = t >> 4, e = t & 15;
  int b = bt * 16 + bq;
  float acc[10];
#pragma unroll
  for (int o = 0; o < 10; o++) acc[o] = 0.f;
  int n0 = nc * 144;
#pragma unroll 1
  for (int n = n0; n < n0 + 144; n++) {
    const float4* up = (const float4*)(u + ((size_t)b * 1152 + n) * 8);
    float4 u0 = up[0], u1 = up[1];
    float cw[10];
    if (cb != nullptr) {
      const unsigned* cp = (const unsigned*)(cb + ((size_t)b * 1152 + n) * 10);
      unsigned c0 = cp[0], c1 = cp[1], c2 = cp[2], c3 = cp[3], c4 = cp[4];
      cw[0] = bf2f_lo(c0); cw[1] = bf2f_hi(c0);
      cw[2] = bf2f_lo(c1); cw[3] = bf2f_hi(c1);
      cw[4] = bf2f_lo(c2); cw[5] = bf2f_hi(c2);
      cw[6] = bf2f_lo(c3); cw[7] = bf2f_hi(c3);
      cw[8] = bf2f_lo(c4); cw[9] = bf2f_hi(c4);
    } else {
#pragma unroll
      for (int o = 0; o < 10; o++) cw[o] = 1.f;
    }
    const float4* wp = (const float4*)(Wt + (size_t)n * 1280 + e * 8);
#pragma unroll
    for (int o = 0; o < 10; o++) {
      float4 w0 = wp[o * 32], w1 = wp[o * 32 + 1];
      float uh = u0.x * w0.x + u0.y * w0.y + u0.z * w0.z + u0.w * w0.w +
                 u1.x * w1.x + u1.y * w1.y + u1.z * w1.z + u1.w * w1.w;
      acc[o] = fmaf(cw[o], uh, acc[o]);
    }
  }
  float* sp = spart + (size_t)nc * 81920 + (size_t)b * 160 + e;
#pragma unroll
  for (int o = 0; o < 10; o++) sp[o * 16] = acc[o];
}

// ---------------- v = squash(prescale * sum_parts); dst = v or dst += v ----------------
__global__ void squash_v_kernel(const float* __restrict__ spart,
                                float* __restrict__ dst, float prescale,
                                int accumulate) {
  int g = blockIdx.x * 256 + threadIdx.x;
  if (g >= 5120) return;
  float r[16];
#pragma unroll
  for (int e = 0; e < 16; e++) r[e] = 0.f;
#pragma unroll
  for (int p = 0; p < 8; p++) {
    const float4* sp = (const float4*)(spart + (size_t)p * 81920 + (size_t)g * 16);
#pragma unroll
    for (int q = 0; q < 4; q++) {
      float4 f4 = sp[q];
      r[4 * q] += f4.x; r[4 * q + 1] += f4.y; r[4 * q + 2] += f4.z; r[4 * q + 3] += f4.w;
    }
  }
  float sn = 0.f;
#pragma unroll
  for (int e = 0; e < 16; e++) { r[e] *= prescale; sn += r[e] * r[e]; }
  float scale = sn / (1.f + sn) / (sqrtf(sn) + 1e-6f);
  float* q = dst + (size_t)g * 16;
#pragma unroll
  for (int e = 0; e < 16; e++) {
    float val = r[e] * scale;
    q[e] = accumulate ? (q[e] + val) : val;
  }
}

// ---------------- logits + softmax -> cb (bf16) ----------------
__global__ __launch_bounds__(128) void logits_c_kernel(
    const float* __restrict__ u, const float* __restrict__ Wt,
    const float* __restrict__ vsum, short* __restrict__ cb) {
  __shared__ float Wl[1280];
  int n = blockIdx.x;
  int t = threadIdx.x;
  for (int i = t; i < 1280; i += 128) Wl[i] = Wt[(size_t)n * 1280 + i];
  __syncthreads();
  float u8[4][8];
#pragma unroll
  for (int k = 0; k < 4; k++) {
    int b = t + 128 * k;
    const float4* up = (const float4*)(u + ((size_t)b * 1152 + n) * 8);
    float4 a = up[0], c = up[1];
    u8[k][0] = a.x; u8[k][1] = a.y; u8[k][2] = a.z; u8[k][3] = a.w;
    u8[k][4] = c.x; u8[k][5] = c.y; u8[k][6] = c.z; u8[k][7] = c.w;
  }
  float dots[4][10];
#pragma unroll 1
  for (int o = 0; o < 10; o++) {
    float4 vs[4][4];
#pragma unroll
    for (int k = 0; k < 4; k++) {
      const float4* vp = (const float4*)(vsum + (size_t)(t + 128 * k) * 160 + o * 16);
#pragma unroll
      for (int q = 0; q < 4; q++) vs[k][q] = vp[q];
    }
    float d0 = 0.f, d1 = 0.f, d2 = 0.f, d3 = 0.f;
#pragma unroll
    for (int e = 0; e < 16; e++) {
      const float4* wp = (const float4*)&Wl[o * 128 + e * 8];
      float4 w0 = wp[0], w1 = wp[1];
      float vse0 = ((const float*)&vs[0][e >> 2])[e & 3];
      float vse1 = ((const float*)&vs[1][e >> 2])[e & 3];
      float vse2 = ((const float*)&vs[2][e >> 2])[e & 3];
      float vse3 = ((const float*)&vs[3][e >> 2])[e & 3];
      float uh0 = u8[0][0]*w0.x + u8[0][1]*w0.y + u8[0][2]*w0.z + u8[0][3]*w0.w +
                  u8[0][4]*w1.x + u8[0][5]*w1.y + u8[0][6]*w1.z + u8[0][7]*w1.w;
      float uh1 = u8[1][0]*w0.x + u8[1][1]*w0.y + u8[1][2]*w0.z + u8[1][3]*w0.w +
                  u8[1][4]*w1.x + u8[1][5]*w1.y + u8[1][6]*w1.z + u8[1][7]*w1.w;
      float uh2 = u8[2][0]*w0.x + u8[2][1]*w0.y + u8[2][2]*w0.z + u8[2][3]*w0.w +
                  u8[2][4]*w1.x + u8[2][5]*w1.y + u8[2][6]*w1.z + u8[2][7]*w1.w;
      float uh3 = u8[3][0]*w0.x + u8[3][1]*w0.y + u8[3][2]*w0.z + u8[3][3]*w0.w +
                  u8[3][4]*w1.x + u8[3][5]*w1.y + u8[3][6]*w1.z + u8[3][7]*w1.w;
      d0 = fmaf(uh0, vse0, d0); d1 = fmaf(uh1, vse1, d1);
      d2 = fmaf(uh2, vse2, d2); d3 = fmaf(uh3, vse3, d3);
    }
    dots[0][o] = d0; dots[1][o] = d1; dots[2][o] = d2; dots[3][o] = d3;
  }
#pragma unroll
  for (int k = 0; k < 4; k++) {
    int b = t + 128 * k;
    float m = dots[k][0];
#pragma unroll
    for (int o = 1; o < 10; o++) m = fmaxf(m, dots[k][o]);
    float sum = 0.f;
#pragma unroll
    for (int o = 0; o < 10; o++) { dots[k][o] = expf(dots[k][o] - m); sum += dots[k][o]; }
    float inv = 1.f / sum;
    unsigned* cp = (unsigned*)(cb + ((size_t)b * 1152 + n) * 10);
#pragma unroll
    for (int q = 0; q < 5; q++) {
      unsigned lo = (unsigned)(unsigned short)f2bf(dots[k][2 * q] * inv);
      unsigned hi = (unsigned)(unsigned short)f2bf(dots[k][2 * q + 1] * inv);
      cp[q] = lo | (hi << 16);
    }
  }
}

extern "C" void kernel_launch(void* const* d_in, const int* in_sizes, int n_in,
                              void* d_out, int out_size, void* d_ws, size_t ws_size,
                              hipStream_t stream) {
  const float* x   = (const float*)d_in[0];
  const float* w1  = (const float*)d_in[1];
  const float* b1v = (const float*)d_in[2];
  const float* w2  = (const float*)d_in[3];
  const float* b2v = (const float*)d_in[4];
  const float* W   = (const float*)d_in[5];
  float* out = (float*)d_out;

  char* ws = (char*)d_ws;
  float* u     = (float*)(ws + OFF_U);
  short* w2b   = (short*)(ws + OFF_A);
  short* cb    = (short*)(ws + OFF_A);
  float* Wt    = (float*)(ws + OFF_WT);
  float* spart = (float*)(ws + OFF_SPART);
  float* vsum  = (float*)(ws + OFF_VSUM);

  transpose_w2b_kernel<<<1024, 256, 0, stream>>>(w2, w2b);
  prep_wt_kernel<<<5760, 256, 0, stream>>>(W, Wt);
  conv_fused_kernel<<<512, 256, 0, stream>>>(x, w1, b1v, w2b, b2v, u);
  squash_u_kernel<<<2304, 256, 0, stream>>>(u);

  // iter 0: uniform c -> s0; vsum = v0
  s_part_kernel<<<dim3(32, 8), 256, 0, stream>>>(u, Wt, nullptr, spart);
  squash_v_kernel<<<20, 256, 0, stream>>>(spart, vsum, 0.1f, 0);
  // iter 1
  logits_c_kernel<<<1152, 128, 0, stream>>>(u, Wt, vsum, cb);
  s_part_kernel<<<dim3(32, 8), 256, 0, stream>>>(u, Wt, cb, spart);
  squash_v_kernel<<<20, 256, 0, stream>>>(spart, vsum, 1.0f, 1);
  // iter 2 -> output
  logits_c_kernel<<<1152, 128, 0, stream>>>(u, Wt, vsum, cb);
  s_part_kernel<<<dim3(32, 8), 256, 0, stream>>>(u, Wt, cb, spart);
  squash_v_kernel<<<20, 256, 0, stream>>>(spart, out, 1.0f, 0);
}

// Round 7
// 1095.964 us; speedup vs baseline: 1.3192x; 1.3192x over previous
//
#include <hip/hip_runtime.h>
#include <math.h>

typedef short short8v __attribute__((ext_vector_type(8)));
typedef float float4v __attribute__((ext_vector_type(4)));

// ---------------- workspace layout (bytes), total 42,139,648 ----------------
#define OFF_U     ((size_t)0)          // h2 then u in-place: 512*1152*8*4 = 18,874,368
#define OFF_A     ((size_t)18874368)   // w2b bf16 10,616,832 | cb bf16 11,796,480 (aliased)
#define OFF_W1T   ((size_t)29491200)   // w1t bf16 256*256*2 = 131,072 (dead after conv)
#define OFF_WT    ((size_t)30670848)   // Wt fp32 [n][o][e][d]: 5,898,240
#define OFF_SPART ((size_t)36569088)   // [16][512][160] f32 = 5,242,880
#define OFF_VSUM  ((size_t)41811968)   // 327,680

__device__ inline short f2bf(float f) {
  union { float f; unsigned u; } v; v.f = f;
  unsigned r = v.u + 0x7FFFu + ((v.u >> 16) & 1u);
  return (short)(r >> 16);
}
__device__ inline float bf2f_lo(unsigned u) {
  union { unsigned u; float f; } v; v.u = u << 16; return v.f;
}
__device__ inline float bf2f_hi(unsigned u) {
  union { unsigned u; float f; } v; v.u = u & 0xFFFF0000u; return v.f;
}

// ---------------- w2 [co][ci][81] fp32 -> w2b [tap][co][ci] bf16 ----------------
__global__ __launch_bounds__(256) void transpose_w2b_kernel(
    const float* __restrict__ w2, short* __restrict__ w2b) {
  __shared__ short tl[81][66];
  int co = blockIdx.x >> 2, ci0 = (blockIdx.x & 3) * 64;
  for (int f = threadIdx.x; f < 64 * 81; f += 256) {
    int cip = f / 81, tap = f % 81;
    tl[tap][cip] = f2bf(w2[((size_t)co * 256 + ci0 + cip) * 81 + tap]);
  }
  __syncthreads();
  for (int f = threadIdx.x; f < 81 * 64; f += 256) {
    int tap = f >> 6, cip = f & 63;
    w2b[((size_t)tap * 256 + co) * 256 + ci0 + cip] = tl[tap][cip];
  }
}

// ---------------- w1 [co][243] fp32 -> w1t [co][256 pad] bf16 ----------------
__global__ __launch_bounds__(256) void prep_w1t_kernel(
    const float* __restrict__ w1, short* __restrict__ w1t) {
  int co = blockIdx.x, t = threadIdx.x;
  w1t[co * 256 + t] = (t < 243) ? f2bf(w1[(size_t)co * 243 + t]) : (short)0;
}

// ---------------- W [n][o][d][e] -> Wt [n][o][e][d] fp32 ----------------
__global__ __launch_bounds__(256) void prep_wt_kernel(
    const float* __restrict__ W, float* __restrict__ Wt) {
  int idx = blockIdx.x * 256 + threadIdx.x;
  if (idx >= 1152 * 1280) return;
  int n = idx / 1280, r = idx - n * 1280;
  int o = r >> 7, de = r & 127;
  int d = de >> 4, e = de & 15;
  Wt[(((size_t)n * 10 + o) * 16 + e) * 8 + d] = W[idx];
}

// ---------------- fused conv1(MFMA)+relu+conv2(MFMA) -> h2 ----------------
// 256 blocks (2 batches), 256 threads (4 waves). Per ci-chunk of 32:
//   conv1: M=400 pos x N=32 co x K=256(pad 243), A gathered from x-LDS, B=w1t global
//   conv2: 81-tap implicit GEMM, M=80 (2b x 40pad), N=256, A=h1l LDS b128, B=w2b global
// NOTE: capsule squash is NOT fused — the torch .view groups 8 consecutive flat
// elements of [256,36], which straddle co boundaries; standalone kernel handles it.
__global__ __launch_bounds__(256, 2) void conv_fused_kernel(
    const float* __restrict__ x, const short* __restrict__ w1t,
    const float* __restrict__ b1v, const short* __restrict__ w2b,
    const float* __restrict__ b2v, float* __restrict__ h2) {
  __shared__ short xsb[4704];        // 2 batches of x, bf16 (9.4 KB)
  __shared__ short h1l[800][40];     // h1 chunk bf16 [bb*400+pos][32ci pad40] (64 KB)

  int b0 = blockIdx.x * 2;
  int t = threadIdx.x;
  int lane = t & 63;
  int wv = t >> 6;
  int l15 = lane & 15, lq = lane >> 4;

  for (int i = t; i < 4704; i += 256) xsb[i] = f2bf(x[(size_t)b0 * 2352 + i]);

  float4v acc2[5][4];
#pragma unroll
  for (int mt = 0; mt < 5; mt++)
#pragma unroll
    for (int nt = 0; nt < 4; nt++) acc2[mt][nt] = (float4v){0.f, 0.f, 0.f, 0.f};

  int rowb[5];
#pragma unroll
  for (int mt = 0; mt < 5; mt++) {
    int m = mt * 16 + l15;
    int ab = (m >= 40) ? 1 : 0;
    int s = m - 40 * ab;
    if (s >= 36) s = 0;
    int sx = (s * 43) >> 8;          // s/6
    int sy = s - 6 * sx;
    rowb[mt] = ab * 400 + sx * 40 + sy * 2;   // row = rowb + kx*20 + ky
  }
  int co[4];
#pragma unroll
  for (int nt = 0; nt < 4; nt++) co[nt] = wv * 64 + nt * 16 + l15;

  int nmt = (wv == 0) ? 7 : 6;
  int px1[7], py1[7];
#pragma unroll
  for (int j = 0; j < 7; j++) {
    int pos = (wv + 4 * j) * 16 + l15;
    if (pos >= 400) pos = 0;
    px1[j] = (pos * 3277) >> 16;     // pos/20
    py1[j] = pos - 20 * px1[j];
  }

  for (int ch = 0; ch < 8; ch++) {
    int ci0 = ch * 32;
    __syncthreads();   // prev conv2 done with h1l (also covers xsb staging)

    // ======== conv1 phase (MFMA), per batch ========
    for (int bb = 0; bb < 2; bb++) {
      const short* xb = &xsb[bb * 2352];
      float4v acc1[7][2];
#pragma unroll
      for (int j = 0; j < 7; j++)
#pragma unroll
        for (int nt = 0; nt < 2; nt++) acc1[j][nt] = (float4v){0.f, 0.f, 0.f, 0.f};
#pragma unroll 1
      for (int kk = 0; kk < 8; kk++) {
        int k0 = kk * 32 + lq * 8;
        int cin = (k0 * 810) >> 16;            // k0/81
        int rem = k0 - 81 * cin;
        int kx = (rem * 57) >> 9;              // rem/9
        int ky = rem - 9 * kx;
        int nv = 243 - k0; if (nv > 8) nv = 8; if (nv < 0) nv = 0;
        int n1 = 9 - ky; if (n1 > 8) n1 = 8;
        int d2 = (kx < 8) ? (28 - ky) : (560 - ky);
        short8v b1f[2];
#pragma unroll
        for (int nt = 0; nt < 2; nt++)
          b1f[nt] = *(const short8v*)(w1t + (size_t)(ci0 + nt * 16 + l15) * 256 + k0);
#pragma unroll
        for (int j = 0; j < 7; j++) {
          if (j < nmt) {
            int o1 = cin * 784 + (px1[j] + kx) * 28 + py1[j] + ky;
            short8v a;
#pragma unroll
            for (int jj = 0; jj < 8; jj++) {
              int idx = (jj < n1) ? (o1 + jj) : (o1 + d2 + jj - n1);
              if (jj >= nv) idx = 0;
              short vsh = xb[idx];
              a[jj] = (jj < nv) ? vsh : (short)0;
            }
#pragma unroll
            for (int nt = 0; nt < 2; nt++)
              acc1[j][nt] = __builtin_amdgcn_mfma_f32_16x16x32_bf16(
                  a, b1f[nt], acc1[j][nt], 0, 0, 0);
          }
        }
      }
      float bs[2];
#pragma unroll
      for (int nt = 0; nt < 2; nt++) bs[nt] = b1v[ci0 + nt * 16 + l15];
#pragma unroll
      for (int j = 0; j < 7; j++) {
        if (j < nmt) {
#pragma unroll
          for (int nt = 0; nt < 2; nt++) {
#pragma unroll
            for (int r = 0; r < 4; r++) {
              int pos = (wv + 4 * j) * 16 + lq * 4 + r;
              float h = acc1[j][nt][r] + bs[nt];
              h1l[bb * 400 + pos][nt * 16 + l15] = f2bf(h > 0.f ? h : 0.f);
            }
          }
        }
      }
    }
    __syncthreads();   // h1l ready

    // ======== conv2 phase: 81 taps, K=32, B-prefetch ring depth 3 ========
    short8v bA[4], bB[4], bC[4];
#pragma unroll
    for (int nt = 0; nt < 4; nt++) {
      const short* wb = w2b + (size_t)co[nt] * 256 + ci0 + lq * 8;
      bA[nt] = *(const short8v*)(wb);
      bB[nt] = *(const short8v*)(wb + 65536);
      bC[nt] = *(const short8v*)(wb + 2 * 65536);
    }
#pragma unroll 1
    for (int tg = 0; tg < 27; tg++) {
#pragma unroll
      for (int sl = 0; sl < 3; sl++) {
        int tap = tg * 3 + sl;
        int kx = (tap * 57) >> 9;
        int ky = tap - 9 * kx;
        int tf = tap + 3; if (tf > 80) tf = 80;
        short8v bcur[4];
#pragma unroll
        for (int nt = 0; nt < 4; nt++)
          bcur[nt] = (sl == 0) ? bA[nt] : (sl == 1) ? bB[nt] : bC[nt];
#pragma unroll
        for (int nt = 0; nt < 4; nt++) {
          short8v bn = *(const short8v*)(w2b + (size_t)tf * 65536 +
                                         (size_t)co[nt] * 256 + ci0 + lq * 8);
          if (sl == 0) bA[nt] = bn; else if (sl == 1) bB[nt] = bn; else bC[nt] = bn;
        }
        int dly = kx * 20 + ky;
#pragma unroll
        for (int mt = 0; mt < 5; mt++) {
          short8v af = *(const short8v*)&h1l[rowb[mt] + dly][lq * 8];
#pragma unroll
          for (int nt = 0; nt < 4; nt++)
            acc2[mt][nt] = __builtin_amdgcn_mfma_f32_16x16x32_bf16(
                af, bcur[nt], acc2[mt][nt], 0, 0, 0);
        }
      }
    }
  }

  // ---- epilogue: bias + store h2[b][co][s] ----
#pragma unroll
  for (int nt = 0; nt < 4; nt++) {
    float bias = b2v[co[nt]];
#pragma unroll
    for (int mt = 0; mt < 5; mt++) {
#pragma unroll
      for (int r = 0; r < 4; r++) {
        int m = mt * 16 + lq * 4 + r;
        int ab = (m >= 40) ? 1 : 0;
        int s = m - 40 * ab;
        if (s < 36 && m < 80)
          h2[((size_t)(b0 + ab) * 256 + co[nt]) * 36 + s] = acc2[mt][nt][r] + bias;
      }
    }
  }
}

// ---------------- squash over consecutive groups of 8 flat floats, IN PLACE ----------------
__global__ void squash_u_kernel(float* __restrict__ hu) {
  int g = blockIdx.x * 256 + threadIdx.x;
  if (g >= 512 * 1152) return;
  float4* p = (float4*)(hu + (size_t)g * 8);
  float4 a = p[0], bq = p[1];
  float sn = a.x*a.x + a.y*a.y + a.z*a.z + a.w*a.w +
             bq.x*bq.x + bq.y*bq.y + bq.z*bq.z + bq.w*bq.w;
  float scale = sn / (1.f + sn) / (sqrtf(sn) + 1e-6f);
  a.x *= scale; a.y *= scale; a.z *= scale; a.w *= scale;
  bq.x *= scale; bq.y *= scale; bq.z *= scale; bq.w *= scale;
  p[0] = a; p[1] = bq;
}

// ---------------- s partials: thread=(b,e), acc[o], no LDS ----------------
__global__ __launch_bounds__(256) void s_part_kernel(
    const float* __restrict__ u, const float* __restrict__ Wt,
    const short* __restrict__ cb, float* __restrict__ spart) {
  int bt = blockIdx.x, nc = blockIdx.y;
  int t = threadIdx.x;
  int bq = t >> 4, e = t & 15;
  int b = bt * 16 + bq;
  float acc[10];
#pragma unroll
  for (int o = 0; o < 10; o++) acc[o] = 0.f;
  int n0 = nc * 72;
#pragma unroll 2
  for (int n = n0; n < n0 + 72; n++) {
    const float4* up = (const float4*)(u + ((size_t)b * 1152 + n) * 8);
    float4 u0 = up[0], u1 = up[1];
    float cw[10];
    if (cb != nullptr) {
      const unsigned* cp = (const unsigned*)(cb + ((size_t)b * 1152 + n) * 10);
      unsigned c0 = cp[0], c1 = cp[1], c2 = cp[2], c3 = cp[3], c4 = cp[4];
      cw[0] = bf2f_lo(c0); cw[1] = bf2f_hi(c0);
      cw[2] = bf2f_lo(c1); cw[3] = bf2f_hi(c1);
      cw[4] = bf2f_lo(c2); cw[5] = bf2f_hi(c2);
      cw[6] = bf2f_lo(c3); cw[7] = bf2f_hi(c3);
      cw[8] = bf2f_lo(c4); cw[9] = bf2f_hi(c4);
    } else {
#pragma unroll
      for (int o = 0; o < 10; o++) cw[o] = 1.f;
    }
    const float4* wp = (const float4*)(Wt + (size_t)n * 1280 + e * 8);
#pragma unroll
    for (int o = 0; o < 10; o++) {
      float4 w0 = wp[o * 32], w1 = wp[o * 32 + 1];
      float uh = u0.x * w0.x + u0.y * w0.y + u0.z * w0.z + u0.w * w0.w +
                 u1.x * w1.x + u1.y * w1.y + u1.z * w1.z + u1.w * w1.w;
      acc[o] = fmaf(cw[o], uh, acc[o]);
    }
  }
  float* sp = spart + (size_t)nc * 81920 + (size_t)b * 160 + e;
#pragma unroll
  for (int o = 0; o < 10; o++) sp[o * 16] = acc[o];
}

// ---------------- v = squash(prescale * sum_parts); dst = v or dst += v ----------------
__global__ void squash_v_kernel(const float* __restrict__ spart,
                                float* __restrict__ dst, float prescale,
                                int accumulate) {
  int g = blockIdx.x * 256 + threadIdx.x;
  if (g >= 5120) return;
  float r[16];
#pragma unroll
  for (int e = 0; e < 16; e++) r[e] = 0.f;
#pragma unroll
  for (int p = 0; p < 16; p++) {
    const float4* sp = (const float4*)(spart + (size_t)p * 81920 + (size_t)g * 16);
#pragma unroll
    for (int q = 0; q < 4; q++) {
      float4 f4 = sp[q];
      r[4 * q] += f4.x; r[4 * q + 1] += f4.y; r[4 * q + 2] += f4.z; r[4 * q + 3] += f4.w;
    }
  }
  float sn = 0.f;
#pragma unroll
  for (int e = 0; e < 16; e++) { r[e] *= prescale; sn += r[e] * r[e]; }
  float scale = sn / (1.f + sn) / (sqrtf(sn) + 1e-6f);
  float* q = dst + (size_t)g * 16;
#pragma unroll
  for (int e = 0; e < 16; e++) {
    float val = r[e] * scale;
    q[e] = accumulate ? (q[e] + val) : val;
  }
}

// ---------------- logits + softmax -> cb (bf16) ----------------
__global__ __launch_bounds__(128) void logits_c_kernel(
    const float* __restrict__ u, const float* __restrict__ Wt,
    const float* __restrict__ vsum, short* __restrict__ cb) {
  __shared__ float Wl[1280];
  int n = blockIdx.x;
  int t = threadIdx.x;
  for (int i = t; i < 1280; i += 128) Wl[i] = Wt[(size_t)n * 1280 + i];
  __syncthreads();
  float u8[4][8];
#pragma unroll
  for (int k = 0; k < 4; k++) {
    int b = t + 128 * k;
    const float4* up = (const float4*)(u + ((size_t)b * 1152 + n) * 8);
    float4 a = up[0], c = up[1];
    u8[k][0] = a.x; u8[k][1] = a.y; u8[k][2] = a.z; u8[k][3] = a.w;
    u8[k][4] = c.x; u8[k][5] = c.y; u8[k][6] = c.z; u8[k][7] = c.w;
  }
  float dots[4][10];
#pragma unroll 1
  for (int o = 0; o < 10; o++) {
    float4 vs[4][4];
#pragma unroll
    for (int k = 0; k < 4; k++) {
      const float4* vp = (const float4*)(vsum + (size_t)(t + 128 * k) * 160 + o * 16);
#pragma unroll
      for (int q = 0; q < 4; q++) vs[k][q] = vp[q];
    }
    float d0 = 0.f, d1 = 0.f, d2 = 0.f, d3 = 0.f;
#pragma unroll
    for (int e = 0; e < 16; e++) {
      const float4* wp = (const float4*)&Wl[o * 128 + e * 8];
      float4 w0 = wp[0], w1 = wp[1];
      float vse0 = ((const float*)&vs[0][e >> 2])[e & 3];
      float vse1 = ((const float*)&vs[1][e >> 2])[e & 3];
      float vse2 = ((const float*)&vs[2][e >> 2])[e & 3];
      float vse3 = ((const float*)&vs[3][e >> 2])[e & 3];
      float uh0 = u8[0][0]*w0.x + u8[0][1]*w0.y + u8[0][2]*w0.z + u8[0][3]*w0.w +
                  u8[0][4]*w1.x + u8[0][5]*w1.y + u8[0][6]*w1.z + u8[0][7]*w1.w;
      float uh1 = u8[1][0]*w0.x + u8[1][1]*w0.y + u8[1][2]*w0.z + u8[1][3]*w0.w +
                  u8[1][4]*w1.x + u8[1][5]*w1.y + u8[1][6]*w1.z + u8[1][7]*w1.w;
      float uh2 = u8[2][0]*w0.x + u8[2][1]*w0.y + u8[2][2]*w0.z + u8[2][3]*w0.w +
                  u8[2][4]*w1.x + u8[2][5]*w1.y + u8[2][6]*w1.z + u8[2][7]*w1.w;
      float uh3 = u8[3][0]*w0.x + u8[3][1]*w0.y + u8[3][2]*w0.z + u8[3][3]*w0.w +
                  u8[3][4]*w1.x + u8[3][5]*w1.y + u8[3][6]*w1.z + u8[3][7]*w1.w;
      d0 = fmaf(uh0, vse0, d0); d1 = fmaf(uh1, vse1, d1);
      d2 = fmaf(uh2, vse2, d2); d3 = fmaf(uh3, vse3, d3);
    }
    dots[0][o] = d0; dots[1][o] = d1; dots[2][o] = d2; dots[3][o] = d3;
  }
#pragma unroll
  for (int k = 0; k < 4; k++) {
    int b = t + 128 * k;
    float m = dots[k][0];
#pragma unroll
    for (int o = 1; o < 10; o++) m = fmaxf(m, dots[k][o]);
    float sum = 0.f;
#pragma unroll
    for (int o = 0; o < 10; o++) { dots[k][o] = expf(dots[k][o] - m); sum += dots[k][o]; }
    float inv = 1.f / sum;
    unsigned* cp = (unsigned*)(cb + ((size_t)b * 1152 + n) * 10);
#pragma unroll
    for (int q = 0; q < 5; q++) {
      unsigned lo = (unsigned)(unsigned short)f2bf(dots[k][2 * q] * inv);
      unsigned hi = (unsigned)(unsigned short)f2bf(dots[k][2 * q + 1] * inv);
      cp[q] = lo | (hi << 16);
    }
  }
}

extern "C" void kernel_launch(void* const* d_in, const int* in_sizes, int n_in,
                              void* d_out, int out_size, void* d_ws, size_t ws_size,
                              hipStream_t stream) {
  const float* x   = (const float*)d_in[0];
  const float* w1  = (const float*)d_in[1];
  const float* b1v = (const float*)d_in[2];
  const float* w2  = (const float*)d_in[3];
  const float* b2v = (const float*)d_in[4];
  const float* W   = (const float*)d_in[5];
  float* out = (float*)d_out;

  char* ws = (char*)d_ws;
  float* u     = (float*)(ws + OFF_U);      // h2 written here, squashed in place
  short* w2b   = (short*)(ws + OFF_A);
  short* cb    = (short*)(ws + OFF_A);      // aliases w2b (dead after conv)
  short* w1t   = (short*)(ws + OFF_W1T);
  float* Wt    = (float*)(ws + OFF_WT);
  float* spart = (float*)(ws + OFF_SPART);
  float* vsum  = (float*)(ws + OFF_VSUM);

  transpose_w2b_kernel<<<1024, 256, 0, stream>>>(w2, w2b);
  prep_w1t_kernel<<<256, 256, 0, stream>>>(w1, w1t);
  prep_wt_kernel<<<5760, 256, 0, stream>>>(W, Wt);
  conv_fused_kernel<<<256, 256, 0, stream>>>(x, w1t, b1v, w2b, b2v, u);
  squash_u_kernel<<<2304, 256, 0, stream>>>(u);

  // iter 0: uniform c -> s0; vsum = v0
  s_part_kernel<<<dim3(32, 16), 256, 0, stream>>>(u, Wt, nullptr, spart);
  squash_v_kernel<<<20, 256, 0, stream>>>(spart, vsum, 0.1f, 0);
  // iter 1
  logits_c_kernel<<<1152, 128, 0, stream>>>(u, Wt, vsum, cb);
  s_part_kernel<<<dim3(32, 16), 256, 0, stream>>>(u, Wt, cb, spart);
  squash_v_kernel<<<20, 256, 0, stream>>>(spart, vsum, 1.0f, 1);
  // iter 2 -> output
  logits_c_kernel<<<1152, 128, 0, stream>>>(u, Wt, vsum, cb);
  s_part_kernel<<<dim3(32, 16), 256, 0, stream>>>(u, Wt, cb, spart);
  squash_v_kernel<<<20, 256, 0, stream>>>(spart, out, 1.0f, 0);
}